// Round 1
// baseline (5617.929 us; speedup 1.0000x reference)
//
#include <hip/hip_runtime.h>
#include <hip/hip_bf16.h>
#include <math.h>

#define THREADS 256

// ---- degree via atomics (self-loop added in dinv transform) ----
__global__ void deg_kernel(const int* __restrict__ dst, float* __restrict__ deg, int E) {
    int i = blockIdx.x * blockDim.x + threadIdx.x;
    int stride = gridDim.x * blockDim.x;
    for (; i < E; i += stride) atomicAdd(&deg[dst[i]], 1.0f);
}

__global__ void dinv_kernel(float* __restrict__ deg, int N) {
    int i = blockIdx.x * blockDim.x + threadIdx.x;
    if (i < N) deg[i] = rsqrtf(deg[i] + 1.0f);
}

// ---- h1lin = x @ W1   (x: [N,128] f32, W1: [128,8]) ----
// one wave = 2 rows; 32 lanes x float4 cover the 128 features coalesced.
__global__ void gemm1_kernel(const float* __restrict__ x, const float* __restrict__ W1,
                             float* __restrict__ out, int N) {
    __shared__ float Wt[8 * 128];  // transposed [h][f]
    for (int i = threadIdx.x; i < 1024; i += blockDim.x) {
        int f = i >> 3, h = i & 7;
        Wt[h * 128 + f] = W1[i];
    }
    __syncthreads();
    const float4* x4 = (const float4*)x;
    const float4* Wt4 = (const float4*)Wt;
    int lane = threadIdx.x & 63;
    int half = lane >> 5;
    int cl = lane & 31;
    int wid = (blockIdx.x * blockDim.x + threadIdx.x) >> 6;
    int nw = (gridDim.x * blockDim.x) >> 6;
    int npairs = (N + 1) >> 1;
    for (int p = wid; p < npairs; p += nw) {
        int row = p * 2 + half;
        float acc[8];
#pragma unroll
        for (int h = 0; h < 8; ++h) acc[h] = 0.f;
        if (row < N) {
            float4 v = x4[(size_t)row * 32 + cl];
#pragma unroll
            for (int h = 0; h < 8; ++h) {
                float4 w = Wt4[h * 32 + cl];
                acc[h] += v.x * w.x + v.y * w.y + v.z * w.z + v.w * w.w;
            }
        }
        // reduce across the 32-lane half (xor masks <32 stay in-half)
#pragma unroll
        for (int m = 16; m >= 1; m >>= 1)
#pragma unroll
            for (int h = 0; h < 8; ++h)
                acc[h] += __shfl_xor(acc[h], m, 64);
        if (cl == 0 && row < N) {
            float4* o = (float4*)(out + (size_t)row * 8);
            o[0] = make_float4(acc[0], acc[1], acc[2], acc[3]);
            o[1] = make_float4(acc[4], acc[5], acc[6], acc[7]);
        }
    }
}

// ---- edge scatter: agg[d] += h[s] * dinv[s]*dinv[d] ----
__global__ void edge_kernel(const int* __restrict__ src, const int* __restrict__ dst,
                            const float* __restrict__ dinv, const float* __restrict__ h,
                            float* __restrict__ agg, int E) {
    int i = blockIdx.x * blockDim.x + threadIdx.x;
    int stride = gridDim.x * blockDim.x;
    for (; i < E; i += stride) {
        int s = src[i], d = dst[i];
        float norm = dinv[s] * dinv[d];
        const float4* hs = (const float4*)(h + (size_t)s * 8);
        float4 a = hs[0], b = hs[1];
        float* ad = agg + (size_t)d * 8;
        atomicAdd(ad + 0, a.x * norm);
        atomicAdd(ad + 1, a.y * norm);
        atomicAdd(ad + 2, a.z * norm);
        atomicAdd(ad + 3, a.w * norm);
        atomicAdd(ad + 4, b.x * norm);
        atomicAdd(ad + 5, b.y * norm);
        atomicAdd(ad + 6, b.z * norm);
        atomicAdd(ad + 7, b.w * norm);
    }
}

// ---- layer-1 finalize (self-loop + bias + relu) fused with h@W2 -> buf ----
__global__ void node_mid_kernel(const float* __restrict__ agg, float* __restrict__ buf,
                                const float* __restrict__ dinv, const float* __restrict__ b1,
                                const float* __restrict__ W2, int N) {
    __shared__ float sW[64];
    __shared__ float sb[8];
    if (threadIdx.x < 64) sW[threadIdx.x] = W2[threadIdx.x];
    if (threadIdx.x < 8) sb[threadIdx.x] = b1[threadIdx.x];
    __syncthreads();
    int i = blockIdx.x * blockDim.x + threadIdx.x;
    if (i >= N) return;
    float di = dinv[i];
    float d2 = di * di;
    const float4* l4 = (const float4*)(buf + (size_t)i * 8);
    const float4* a4 = (const float4*)(agg + (size_t)i * 8);
    float4 l0 = l4[0], l1 = l4[1];
    float4 a0 = a4[0], a1 = a4[1];
    float h1[8];
    h1[0] = fmaxf(a0.x + l0.x * d2 + sb[0], 0.f);
    h1[1] = fmaxf(a0.y + l0.y * d2 + sb[1], 0.f);
    h1[2] = fmaxf(a0.z + l0.z * d2 + sb[2], 0.f);
    h1[3] = fmaxf(a0.w + l0.w * d2 + sb[3], 0.f);
    h1[4] = fmaxf(a1.x + l1.x * d2 + sb[4], 0.f);
    h1[5] = fmaxf(a1.y + l1.y * d2 + sb[5], 0.f);
    h1[6] = fmaxf(a1.z + l1.z * d2 + sb[6], 0.f);
    h1[7] = fmaxf(a1.w + l1.w * d2 + sb[7], 0.f);
    float h2[8];
#pragma unroll
    for (int o = 0; o < 8; ++o) h2[o] = 0.f;
#pragma unroll
    for (int k = 0; k < 8; ++k)
#pragma unroll
        for (int o = 0; o < 8; ++o) h2[o] += h1[k] * sW[k * 8 + o];
    float4* o4 = (float4*)(buf + (size_t)i * 8);
    o4[0] = make_float4(h2[0], h2[1], h2[2], h2[3]);
    o4[1] = make_float4(h2[4], h2[5], h2[6], h2[7]);
}

// ---- layer-2 finalize fused with per-graph readout (batch is sorted) ----
__global__ void node_out_kernel(const float* __restrict__ agg, const float* __restrict__ buf,
                                const float* __restrict__ dinv, const float* __restrict__ b2,
                                const int* __restrict__ batch, float* __restrict__ outs, int N) {
    __shared__ float sb[8];
    if (threadIdx.x < 8) sb[threadIdx.x] = b2[threadIdx.x];
    __syncthreads();
    int i = blockIdx.x * blockDim.x + threadIdx.x;
    float h2[8];
    int g = -1;
    if (i < N) {
        float di = dinv[i];
        float d2 = di * di;
        const float4* l4 = (const float4*)(buf + (size_t)i * 8);
        const float4* a4 = (const float4*)(agg + (size_t)i * 8);
        float4 l0 = l4[0], l1 = l4[1];
        float4 a0 = a4[0], a1 = a4[1];
        h2[0] = fmaxf(a0.x + l0.x * d2 + sb[0], 0.f);
        h2[1] = fmaxf(a0.y + l0.y * d2 + sb[1], 0.f);
        h2[2] = fmaxf(a0.z + l0.z * d2 + sb[2], 0.f);
        h2[3] = fmaxf(a0.w + l0.w * d2 + sb[3], 0.f);
        h2[4] = fmaxf(a1.x + l1.x * d2 + sb[4], 0.f);
        h2[5] = fmaxf(a1.y + l1.y * d2 + sb[5], 0.f);
        h2[6] = fmaxf(a1.z + l1.z * d2 + sb[6], 0.f);
        h2[7] = fmaxf(a1.w + l1.w * d2 + sb[7], 0.f);
        g = batch[i];
    } else {
#pragma unroll
        for (int o = 0; o < 8; ++o) h2[o] = 0.f;
    }
    int g0 = __shfl(g, 0, 64);
    bool uni = __all(g == g0);
    if (uni) {
        // whole wave in one graph: reduce in-wave, 8 atomics total
#pragma unroll
        for (int m = 32; m >= 1; m >>= 1)
#pragma unroll
            for (int o = 0; o < 8; ++o) h2[o] += __shfl_xor(h2[o], m, 64);
        if ((threadIdx.x & 63) == 0 && g0 >= 0) {
            float* og = outs + (size_t)g0 * 8;
#pragma unroll
            for (int o = 0; o < 8; ++o) atomicAdd(og + o, h2[o]);
        }
    } else if (i < N) {
        float* og = outs + (size_t)g * 8;
#pragma unroll
        for (int o = 0; o < 8; ++o) atomicAdd(og + o, h2[o]);
    }
}

// ---- logits = outs @ Wl + bl ; sigmoid ----
__global__ void readout_kernel(const float* __restrict__ outs, const float* __restrict__ Wl,
                               const float* __restrict__ bl, float* __restrict__ out, int G) {
    int gidx = blockIdx.x * blockDim.x + threadIdx.x;
    if (gidx >= G) return;
    float acc = bl[0];
#pragma unroll
    for (int o = 0; o < 8; ++o) acc += outs[(size_t)gidx * 8 + o] * Wl[o];
    out[gidx] = 1.f / (1.f + expf(-acc));
}

extern "C" void kernel_launch(void* const* d_in, const int* in_sizes, int n_in,
                              void* d_out, int out_size, void* d_ws, size_t ws_size,
                              hipStream_t stream) {
    const float* x  = (const float*)d_in[0];
    const float* W1 = (const float*)d_in[1];
    const float* b1 = (const float*)d_in[2];
    const float* W2 = (const float*)d_in[3];
    const float* b2 = (const float*)d_in[4];
    const float* Wl = (const float*)d_in[5];
    const float* bl = (const float*)d_in[6];
    const int* ei    = (const int*)d_in[7];
    const int* batch = (const int*)d_in[8];

    const int N = in_sizes[8];
    const int E = in_sizes[7] / 2;
    const int G = out_size;
    const int* src = ei;
    const int* dst = ei + E;

    // workspace layout (all offsets 256B-aligned for N=200000)
    char* ws = (char*)d_ws;
    float* dinv = (float*)ws;                                   // N floats (deg first)
    float* bufA = (float*)(ws + (size_t)N * 4);                 // N*8 (h1lin -> h2lin)
    float* aggB = (float*)(ws + (size_t)N * 4 + (size_t)N * 32);// N*8 (agg, reused)
    float* outs = (float*)(ws + (size_t)N * 4 + 2 * (size_t)N * 32); // G*8

    hipMemsetAsync(dinv, 0, (size_t)N * 4, stream);
    hipMemsetAsync(aggB, 0, (size_t)N * 32, stream);
    hipMemsetAsync(outs, 0, (size_t)G * 32, stream);

    int nb_nodes = (N + THREADS - 1) / THREADS;
    int nb_edges = (E + THREADS - 1) / THREADS;

    deg_kernel<<<nb_edges, THREADS, 0, stream>>>(dst, dinv, E);
    dinv_kernel<<<nb_nodes, THREADS, 0, stream>>>(dinv, N);

    gemm1_kernel<<<4096, THREADS, 0, stream>>>(x, W1, bufA, N);

    edge_kernel<<<nb_edges, THREADS, 0, stream>>>(src, dst, dinv, bufA, aggB, E);
    node_mid_kernel<<<nb_nodes, THREADS, 0, stream>>>(aggB, bufA, dinv, b1, W2, N);

    hipMemsetAsync(aggB, 0, (size_t)N * 32, stream);
    edge_kernel<<<nb_edges, THREADS, 0, stream>>>(src, dst, dinv, bufA, aggB, E);
    node_out_kernel<<<nb_nodes, THREADS, 0, stream>>>(aggB, bufA, dinv, b2, batch, outs, N);

    readout_kernel<<<(G + THREADS - 1) / THREADS, THREADS, 0, stream>>>(outs, Wl, bl, (float*)d_out, G);
}

// Round 2
// 839.049 us; speedup vs baseline: 6.6956x; 6.6956x over previous
//
#include <hip/hip_runtime.h>
#include <hip/hip_bf16.h>
#include <math.h>

#define THREADS 256

static __host__ __device__ inline size_t A256(size_t x) { return (x + 255) & ~(size_t)255; }

// ================= CSR build =================

// pos[e] = rank of edge e within its dst bucket; count[d] ends as indegree
__global__ void hist_pos_kernel(const int* __restrict__ dst, int* __restrict__ count,
                                int* __restrict__ pos, int E) {
    int i = blockIdx.x * blockDim.x + threadIdx.x;
    int stride = gridDim.x * blockDim.x;
    for (; i < E; i += stride) pos[i] = atomicAdd(&count[dst[i]], 1);
}

__global__ void hist_kernel(const int* __restrict__ dst, int* __restrict__ count, int E) {
    int i = blockIdx.x * blockDim.x + threadIdx.x;
    int stride = gridDim.x * blockDim.x;
    for (; i < E; i += stride) atomicAdd(&count[dst[i]], 1);
}

// block sums over 1024-element chunks
__global__ void scan_sums_kernel(const int* __restrict__ count, int* __restrict__ bsums, int N) {
    __shared__ int sd[256];
    int t = threadIdx.x;
    int base = blockIdx.x * 1024;
    int s = 0;
#pragma unroll
    for (int k = 0; k < 4; ++k) {
        int i = base + t * 4 + k;
        if (i < N) s += count[i];
    }
    sd[t] = s;
    __syncthreads();
    for (int off = 128; off > 0; off >>= 1) {
        if (t < off) sd[t] += sd[t + off];
        __syncthreads();
    }
    if (t == 0) bsums[blockIdx.x] = sd[0];
}

// exclusive scan of bsums (NB <= 1024) in a single block
__global__ void scan_tops_kernel(int* __restrict__ bsums, int NB) {
    __shared__ int ls[256];
    int t = threadIdx.x;
    int v[4];
    int tsum = 0;
#pragma unroll
    for (int k = 0; k < 4; ++k) {
        int i = t * 4 + k;
        v[k] = (i < NB) ? bsums[i] : 0;
        tsum += v[k];
    }
    ls[t] = tsum;
    __syncthreads();
    for (int off = 1; off < 256; off <<= 1) {
        int add = (t >= off) ? ls[t - off] : 0;
        __syncthreads();
        ls[t] += add;
        __syncthreads();
    }
    int p = ls[t] - tsum;  // exclusive
#pragma unroll
    for (int k = 0; k < 4; ++k) {
        int i = t * 4 + k;
        if (i < NB) { int old = v[k]; bsums[i] = p; p += old; }
    }
}

// rowptr[i] = exclusive scan of count, plus rowptr[N] = E
__global__ void scan_final_kernel(const int* __restrict__ count, const int* __restrict__ bsums,
                                  int* __restrict__ rowptr, int N, int E) {
    __shared__ int ls[256];
    int t = threadIdx.x;
    int base = blockIdx.x * 1024;
    int v[4];
    int tsum = 0;
#pragma unroll
    for (int k = 0; k < 4; ++k) {
        int i = base + t * 4 + k;
        v[k] = (i < N) ? count[i] : 0;
        tsum += v[k];
    }
    ls[t] = tsum;
    __syncthreads();
    for (int off = 1; off < 256; off <<= 1) {
        int add = (t >= off) ? ls[t - off] : 0;
        __syncthreads();
        ls[t] += add;
        __syncthreads();
    }
    int p = ls[t] - tsum + bsums[blockIdx.x];
#pragma unroll
    for (int k = 0; k < 4; ++k) {
        int i = base + t * 4 + k;
        if (i < N) { rowptr[i] = p; p += v[k]; }
    }
    if (blockIdx.x == 0 && t == 0) rowptr[N] = E;
}

__global__ void dinv_kernel(const int* __restrict__ count, float* __restrict__ dinv, int N) {
    int i = blockIdx.x * blockDim.x + threadIdx.x;
    if (i < N) dinv[i] = rsqrtf((float)count[i] + 1.0f);
}

__global__ void copy_int_kernel(const int* __restrict__ a, int* __restrict__ b, int n) {
    int i = blockIdx.x * blockDim.x + threadIdx.x;
    if (i < n) b[i] = a[i];
}

// fill using precomputed pos (no atomics)
__global__ void fill_pos_kernel(const int* __restrict__ src, const int* __restrict__ dst,
                                const int* __restrict__ pos, const int* __restrict__ rowptr,
                                const float* __restrict__ dinv, int* __restrict__ csr_src,
                                float* __restrict__ csr_norm, int E) {
    int i = blockIdx.x * blockDim.x + threadIdx.x;
    int stride = gridDim.x * blockDim.x;
    for (; i < E; i += stride) {
        int d = dst[i], s = src[i];
        int slot = rowptr[d] + pos[i];
        csr_src[slot] = s;
        if (csr_norm) csr_norm[slot] = dinv[s] * dinv[d];
    }
}

// fill using cursor atomics (fallback, less ws)
__global__ void fill_cur_kernel(const int* __restrict__ src, const int* __restrict__ dst,
                                int* __restrict__ cursor, const float* __restrict__ dinv,
                                int* __restrict__ csr_src, float* __restrict__ csr_norm, int E) {
    int i = blockIdx.x * blockDim.x + threadIdx.x;
    int stride = gridDim.x * blockDim.x;
    for (; i < E; i += stride) {
        int d = dst[i], s = src[i];
        int slot = atomicAdd(&cursor[d], 1);
        csr_src[slot] = s;
        if (csr_norm) csr_norm[slot] = dinv[s] * dinv[d];
    }
}

// ================= GEMM1: h1lin = x @ W1 (x: [N,128], W1: [128,8]) =================
__global__ void gemm1_kernel(const float* __restrict__ x, const float* __restrict__ W1,
                             float* __restrict__ out, int N) {
    __shared__ float Wt[8 * 128];  // transposed [h][f]
    for (int i = threadIdx.x; i < 1024; i += blockDim.x) {
        int f = i >> 3, h = i & 7;
        Wt[h * 128 + f] = W1[i];
    }
    __syncthreads();
    const float4* x4 = (const float4*)x;
    const float4* Wt4 = (const float4*)Wt;
    int lane = threadIdx.x & 63;
    int half = lane >> 5;
    int cl = lane & 31;
    int wid = (blockIdx.x * blockDim.x + threadIdx.x) >> 6;
    int nw = (gridDim.x * blockDim.x) >> 6;
    int npairs = (N + 1) >> 1;
    for (int p = wid; p < npairs; p += nw) {
        int row = p * 2 + half;
        float acc[8];
#pragma unroll
        for (int h = 0; h < 8; ++h) acc[h] = 0.f;
        if (row < N) {
            float4 v = x4[(size_t)row * 32 + cl];
#pragma unroll
            for (int h = 0; h < 8; ++h) {
                float4 w = Wt4[h * 32 + cl];
                acc[h] += v.x * w.x + v.y * w.y + v.z * w.z + v.w * w.w;
            }
        }
#pragma unroll
        for (int m = 16; m >= 1; m >>= 1)
#pragma unroll
            for (int h = 0; h < 8; ++h)
                acc[h] += __shfl_xor(acc[h], m, 64);
        if (cl == 0 && row < N) {
            float4* o = (float4*)(out + (size_t)row * 8);
            o[0] = make_float4(acc[0], acc[1], acc[2], acc[3]);
            o[1] = make_float4(acc[4], acc[5], acc[6], acc[7]);
        }
    }
}

// ================= gather aggregation (one wave per node) =================
// lane = grp*8 + j : grp indexes edges (8 in flight), j = feature index.
// LAYER 1: out = relu(agg + d2*self + b) @ W2 ;  LAYER 2: out = relu(agg + d2*self + b)
template <int LAYER>
__global__ void gather_kernel(const int* __restrict__ rowptr, const int* __restrict__ csr_src,
                              const float* __restrict__ csr_norm, const float* __restrict__ dinv,
                              const float* __restrict__ hin, const float* __restrict__ bias,
                              const float* __restrict__ W2, float* __restrict__ hout, int N) {
    __shared__ float sW[64];
    __shared__ float sb[8];
    if (LAYER == 1 && threadIdx.x < 64) sW[threadIdx.x] = W2[threadIdx.x];
    if (threadIdx.x < 8) sb[threadIdx.x] = bias[threadIdx.x];
    __syncthreads();
    int node = (blockIdx.x * blockDim.x + threadIdx.x) >> 6;
    if (node >= N) return;
    int lane = threadIdx.x & 63;
    int grp = lane >> 3, j = lane & 7;
    int rs = rowptr[node], re = rowptr[node + 1];
    float acc = 0.f;
    float dd = dinv[node];
    if (csr_norm) {
        for (int e = rs + grp; e < re; e += 8) {
            int s = csr_src[e];
            acc += csr_norm[e] * hin[(size_t)s * 8 + j];
        }
    } else {
        for (int e = rs + grp; e < re; e += 8) {
            int s = csr_src[e];
            acc += dd * dinv[s] * hin[(size_t)s * 8 + j];
        }
    }
    acc += __shfl_xor(acc, 8, 64);
    acc += __shfl_xor(acc, 16, 64);
    acc += __shfl_xor(acc, 32, 64);
    float hv = fmaxf(acc + dd * dd * hin[(size_t)node * 8 + j] + sb[j], 0.f);
    float outv;
    if (LAYER == 1) {
        outv = 0.f;
        int gb = lane & ~7;
#pragma unroll
        for (int k = 0; k < 8; ++k) outv += __shfl(hv, gb + k, 64) * sW[k * 8 + j];
    } else {
        outv = hv;
    }
    if (grp == 0) hout[(size_t)node * 8 + j] = outv;
}

// ================= readout: per-graph sum of h2 rows (batch sorted) =================
__global__ void readout_sum_kernel(const float* __restrict__ h2, const int* __restrict__ batch,
                                   float* __restrict__ outs, int N) {
    int i = blockIdx.x * blockDim.x + threadIdx.x;
    float v[8];
    int g = -1;
    if (i < N) {
        const float4* p4 = (const float4*)(h2 + (size_t)i * 8);
        float4 a = p4[0], b = p4[1];
        v[0] = a.x; v[1] = a.y; v[2] = a.z; v[3] = a.w;
        v[4] = b.x; v[5] = b.y; v[6] = b.z; v[7] = b.w;
        g = batch[i];
    } else {
#pragma unroll
        for (int o = 0; o < 8; ++o) v[o] = 0.f;
    }
    int g0 = __shfl(g, 0, 64);
    bool uni = __all(g == g0);
    if (uni) {
#pragma unroll
        for (int m = 32; m >= 1; m >>= 1)
#pragma unroll
            for (int o = 0; o < 8; ++o) v[o] += __shfl_xor(v[o], m, 64);
        if ((threadIdx.x & 63) == 0 && g0 >= 0) {
            float* og = outs + (size_t)g0 * 8;
#pragma unroll
            for (int o = 0; o < 8; ++o) atomicAdd(og + o, v[o]);
        }
    } else if (i < N) {
        float* og = outs + (size_t)g * 8;
#pragma unroll
        for (int o = 0; o < 8; ++o) atomicAdd(og + o, v[o]);
    }
}

__global__ void logits_kernel(const float* __restrict__ outs, const float* __restrict__ Wl,
                              const float* __restrict__ bl, float* __restrict__ out, int G) {
    int gidx = blockIdx.x * blockDim.x + threadIdx.x;
    if (gidx >= G) return;
    float acc = bl[0];
#pragma unroll
    for (int o = 0; o < 8; ++o) acc += outs[(size_t)gidx * 8 + o] * Wl[o];
    out[gidx] = 1.f / (1.f + expf(-acc));
}

// ================= round-1 fallback kernels (only used if ws too small) =================
__global__ void fb_deg_kernel(const int* __restrict__ dst, float* __restrict__ deg, int E) {
    int i = blockIdx.x * blockDim.x + threadIdx.x;
    int stride = gridDim.x * blockDim.x;
    for (; i < E; i += stride) atomicAdd(&deg[dst[i]], 1.0f);
}
__global__ void fb_dinv_kernel(float* __restrict__ deg, int N) {
    int i = blockIdx.x * blockDim.x + threadIdx.x;
    if (i < N) deg[i] = rsqrtf(deg[i] + 1.0f);
}
__global__ void fb_edge_kernel(const int* __restrict__ src, const int* __restrict__ dst,
                               const float* __restrict__ dinv, const float* __restrict__ h,
                               float* __restrict__ agg, int E) {
    int i = blockIdx.x * blockDim.x + threadIdx.x;
    int stride = gridDim.x * blockDim.x;
    for (; i < E; i += stride) {
        int s = src[i], d = dst[i];
        float norm = dinv[s] * dinv[d];
        const float4* hs = (const float4*)(h + (size_t)s * 8);
        float4 a = hs[0], b = hs[1];
        float* ad = agg + (size_t)d * 8;
        atomicAdd(ad + 0, a.x * norm); atomicAdd(ad + 1, a.y * norm);
        atomicAdd(ad + 2, a.z * norm); atomicAdd(ad + 3, a.w * norm);
        atomicAdd(ad + 4, b.x * norm); atomicAdd(ad + 5, b.y * norm);
        atomicAdd(ad + 6, b.z * norm); atomicAdd(ad + 7, b.w * norm);
    }
}
__global__ void fb_node_kernel(const float* __restrict__ agg, const float* __restrict__ bin,
                               float* __restrict__ bout, const float* __restrict__ dinv,
                               const float* __restrict__ bias, const float* __restrict__ W2,
                               int use_w2, int N) {
    __shared__ float sW[64];
    __shared__ float sb[8];
    if (threadIdx.x < 64) sW[threadIdx.x] = use_w2 ? W2[threadIdx.x] : 0.f;
    if (threadIdx.x < 8) sb[threadIdx.x] = bias[threadIdx.x];
    __syncthreads();
    int i = blockIdx.x * blockDim.x + threadIdx.x;
    if (i >= N) return;
    float di = dinv[i];
    float d2 = di * di;
    const float4* l4 = (const float4*)(bin + (size_t)i * 8);
    const float4* a4 = (const float4*)(agg + (size_t)i * 8);
    float4 l0 = l4[0], l1 = l4[1];
    float4 a0 = a4[0], a1 = a4[1];
    float h1[8];
    h1[0] = fmaxf(a0.x + l0.x * d2 + sb[0], 0.f);
    h1[1] = fmaxf(a0.y + l0.y * d2 + sb[1], 0.f);
    h1[2] = fmaxf(a0.z + l0.z * d2 + sb[2], 0.f);
    h1[3] = fmaxf(a0.w + l0.w * d2 + sb[3], 0.f);
    h1[4] = fmaxf(a1.x + l1.x * d2 + sb[4], 0.f);
    h1[5] = fmaxf(a1.y + l1.y * d2 + sb[5], 0.f);
    h1[6] = fmaxf(a1.z + l1.z * d2 + sb[6], 0.f);
    h1[7] = fmaxf(a1.w + l1.w * d2 + sb[7], 0.f);
    float h2[8];
    if (use_w2) {
#pragma unroll
        for (int o = 0; o < 8; ++o) h2[o] = 0.f;
#pragma unroll
        for (int k = 0; k < 8; ++k)
#pragma unroll
            for (int o = 0; o < 8; ++o) h2[o] += h1[k] * sW[k * 8 + o];
    } else {
#pragma unroll
        for (int o = 0; o < 8; ++o) h2[o] = h1[o];
    }
    float4* o4 = (float4*)(bout + (size_t)i * 8);
    o4[0] = make_float4(h2[0], h2[1], h2[2], h2[3]);
    o4[1] = make_float4(h2[4], h2[5], h2[6], h2[7]);
}

extern "C" void kernel_launch(void* const* d_in, const int* in_sizes, int n_in,
                              void* d_out, int out_size, void* d_ws, size_t ws_size,
                              hipStream_t stream) {
    const float* x  = (const float*)d_in[0];
    const float* W1 = (const float*)d_in[1];
    const float* b1 = (const float*)d_in[2];
    const float* W2 = (const float*)d_in[3];
    const float* b2 = (const float*)d_in[4];
    const float* Wl = (const float*)d_in[5];
    const float* bl = (const float*)d_in[6];
    const int* ei    = (const int*)d_in[7];
    const int* batch = (const int*)d_in[8];

    const int N = in_sizes[8];
    const int E = in_sizes[7] / 2;
    const int G = out_size;
    const int* src = ei;
    const int* dst = ei + E;

    const int NB = (N + 1023) / 1024;  // scan blocks (<= 1024)

    // ---- workspace layout ----
    char* ws = (char*)d_ws;
    size_t off = 0;
    size_t o_count  = off; off = A256(off + (size_t)N * 4);
    size_t o_dinv   = off; off = A256(off + (size_t)N * 4);
    size_t o_rowptr = off; off = A256(off + (size_t)(N + 1) * 4);
    size_t o_bsums  = off; off = A256(off + 4096);
    size_t o_bufA   = off; off = A256(off + (size_t)N * 32);
    size_t o_bufB   = off; off = A256(off + (size_t)N * 32);
    size_t o_outs   = off; off = A256(off + (size_t)G * 32);
    size_t o_csrsrc = off; off = A256(off + (size_t)E * 4);
    size_t base_end = off;
    size_t o_cursor = base_end;                       // cursor variant: N ints
    size_t cur_end  = A256(base_end + (size_t)N * 4);
    size_t o_pos    = base_end;                       // pos variant: E ints
    size_t pos_end  = A256(base_end + (size_t)E * 4);
    size_t o_norm   = pos_end;                        // norm on top of pos
    size_t norm_end = A256(pos_end + (size_t)E * 4);

    bool have_pos  = ws_size >= pos_end;
    bool have_norm = ws_size >= norm_end;
    bool have_csr  = ws_size >= cur_end;

    int nb_nodes = (N + THREADS - 1) / THREADS;

    if (!have_csr) {
        // ---- round-1 full-atomic fallback ----
        float* dinv = (float*)(ws + o_count);
        float* bufA = (float*)(ws + (size_t)N * 4);
        float* aggB = (float*)(ws + (size_t)N * 4 + (size_t)N * 32);
        float* outs = (float*)(ws + (size_t)N * 4 + 2 * (size_t)N * 32);
        hipMemsetAsync(dinv, 0, (size_t)N * 4, stream);
        hipMemsetAsync(aggB, 0, (size_t)N * 32, stream);
        hipMemsetAsync(outs, 0, (size_t)G * 32, stream);
        fb_deg_kernel<<<4096, THREADS, 0, stream>>>(dst, dinv, E);
        fb_dinv_kernel<<<nb_nodes, THREADS, 0, stream>>>(dinv, N);
        gemm1_kernel<<<4096, THREADS, 0, stream>>>(x, W1, bufA, N);
        fb_edge_kernel<<<4096, THREADS, 0, stream>>>(src, dst, dinv, bufA, aggB, E);
        fb_node_kernel<<<nb_nodes, THREADS, 0, stream>>>(aggB, bufA, bufA, dinv, b1, W2, 1, N);
        hipMemsetAsync(aggB, 0, (size_t)N * 32, stream);
        fb_edge_kernel<<<4096, THREADS, 0, stream>>>(src, dst, dinv, bufA, aggB, E);
        fb_node_kernel<<<nb_nodes, THREADS, 0, stream>>>(aggB, bufA, bufA, dinv, b2, nullptr, 0, N);
        readout_sum_kernel<<<nb_nodes, THREADS, 0, stream>>>(bufA, batch, outs, N);
        logits_kernel<<<(G + THREADS - 1) / THREADS, THREADS, 0, stream>>>(outs, Wl, bl, (float*)d_out, G);
        return;
    }

    int*   count   = (int*)(ws + o_count);
    float* dinv    = (float*)(ws + o_dinv);
    int*   rowptr  = (int*)(ws + o_rowptr);
    int*   bsums   = (int*)(ws + o_bsums);
    float* bufA    = (float*)(ws + o_bufA);
    float* bufB    = (float*)(ws + o_bufB);
    float* outs    = (float*)(ws + o_outs);
    int*   csr_src = (int*)(ws + o_csrsrc);
    int*   pos     = have_pos ? (int*)(ws + o_pos) : nullptr;
    int*   cursor  = have_pos ? nullptr : (int*)(ws + o_cursor);
    float* csr_nrm = have_norm ? (float*)(ws + o_norm) : nullptr;

    hipMemsetAsync(count, 0, (size_t)N * 4, stream);
    hipMemsetAsync(outs, 0, (size_t)G * 32, stream);

    // 1. histogram (+pos ranks)
    if (have_pos)
        hist_pos_kernel<<<4096, THREADS, 0, stream>>>(dst, count, pos, E);
    else
        hist_kernel<<<4096, THREADS, 0, stream>>>(dst, count, E);

    // 2. scan -> rowptr
    scan_sums_kernel<<<NB, 256, 0, stream>>>(count, bsums, N);
    scan_tops_kernel<<<1, 256, 0, stream>>>(bsums, NB);
    scan_final_kernel<<<NB, 256, 0, stream>>>(count, bsums, rowptr, N, E);

    // 3. dinv
    dinv_kernel<<<nb_nodes, THREADS, 0, stream>>>(count, dinv, N);

    // 4. fill CSR
    if (have_pos) {
        fill_pos_kernel<<<4096, THREADS, 0, stream>>>(src, dst, pos, rowptr, dinv, csr_src, csr_nrm, E);
    } else {
        copy_int_kernel<<<nb_nodes, THREADS, 0, stream>>>(rowptr, cursor, N);
        fill_cur_kernel<<<4096, THREADS, 0, stream>>>(src, dst, cursor, dinv, csr_src, csr_nrm, E);
    }

    // 5. x @ W1
    gemm1_kernel<<<4096, THREADS, 0, stream>>>(x, W1, bufA, N);

    // 6. layer 1 gather (+ReLU +W2), layer 2 gather (+ReLU)
    int nb_gather = (N * 64 + THREADS - 1) / THREADS;
    gather_kernel<1><<<nb_gather, THREADS, 0, stream>>>(rowptr, csr_src, csr_nrm, dinv, bufA, b1, W2, bufB, N);
    gather_kernel<2><<<nb_gather, THREADS, 0, stream>>>(rowptr, csr_src, csr_nrm, dinv, bufB, b2, W2, bufA, N);

    // 7. readout
    readout_sum_kernel<<<nb_nodes, THREADS, 0, stream>>>(bufA, batch, outs, N);
    logits_kernel<<<(G + THREADS - 1) / THREADS, THREADS, 0, stream>>>(outs, Wl, bl, (float*)d_out, G);
}